// Round 6
// baseline (6997.561 us; speedup 1.0000x reference)
//
#include <hip/hip_runtime.h>
#include <math.h>

typedef unsigned short u16;
typedef unsigned int u32;
typedef __attribute__((ext_vector_type(8))) short short8;
typedef __attribute__((ext_vector_type(4))) float f32x4;
typedef __attribute__((ext_vector_type(2))) float f32x2;
typedef __attribute__((ext_vector_type(4))) unsigned int u32x4;

__device__ __forceinline__ u16 f32_to_bf16(float x) {
    union { float f; unsigned int u; } v; v.f = x;
    unsigned int u = v.u;
    return (u16)((u + 0x7FFFu + ((u >> 16) & 1u)) >> 16);
}
__device__ __forceinline__ float bf16_to_f32(u16 h) {
    union { unsigned int u; float f; } v; v.u = ((unsigned int)h) << 16; return v.f;
}

// async global->LDS, 16B per lane; LDS dest is wave-uniform base + lane*16
__device__ __forceinline__ void gload16(const u16* g, u16* l) {
    __builtin_amdgcn_global_load_lds(
        (const __attribute__((address_space(1))) void*)g,
        (__attribute__((address_space(3))) void*)l, 16, 0, 0);
}

// ---------------------------------------------------------------------------
// split fp32 [N][K] (optionally gate-permuted rows) -> bf16 hi/lo [Npad][Kpad]
// perm=1: source row for dst row n is (n&3)*(N/4) + (n>>2)   (c = j*4+g)
// ---------------------------------------------------------------------------
__global__ void split_pad_kernel(const float* __restrict__ src,
                                 u16* __restrict__ hi, u16* __restrict__ lo,
                                 int N, int K, int Npad, int Kpad, int perm)
{
    int idx = blockIdx.x * 256 + threadIdx.x;
    if (idx >= Npad * Kpad) return;
    int n = idx / Kpad, k = idx - n * Kpad;
    float x = 0.f;
    if (n < N && k < K) {
        int srow = n;
        if (perm) { int dout = N >> 2; srow = (n & 3) * dout + (n >> 2); }
        x = src[(size_t)srow * K + k];
    }
    u16 h = f32_to_bf16(x);
    hi[idx] = h;
    lo[idx] = f32_to_bf16(x - bf16_to_f32(h));
}

// pack fp32 [B][K] -> u32 (hi | lo<<16) [B][Kpad]
__global__ void pack_h0_kernel(const float* __restrict__ src, u32* __restrict__ dst,
                               int Brows, int K, int Kpad)
{
    int idx = blockIdx.x * 256 + threadIdx.x;
    if (idx >= Brows * Kpad) return;
    int b = idx / Kpad, k = idx - b * Kpad;
    float x = (k < K) ? src[(size_t)b * K + k] : 0.f;
    u16 h = f32_to_bf16(x);
    u16 l = f32_to_bf16(x - bf16_to_f32(h));
    dst[idx] = (u32)h | ((u32)l << 16);
}

__global__ void bias_perm_kernel(const float* __restrict__ bi,
                                 const float* __restrict__ bh,
                                 float* __restrict__ out, int N4)
{
    int c = blockIdx.x * 256 + threadIdx.x;
    if (c >= N4) return;
    int dout = N4 >> 2;
    int s = (c & 3) * dout + (c >> 2);
    out[c] = bi[s] + bh[s];
}

// ---------------------------------------------------------------------------
// C[M][ldc] = A @ W^T + bias, bf16x3 MFMA.
// amode 0: Af32 fp32, split on the fly, reg-staged ds_write path.
// amode 1: pre-split bf16 -> global_load_lds width-16 staging (linear LDS,
//          inverse-XOR pre-swizzled global source; one wave per buffer).
// 1-D grid, supergrouped: NSUB n-tiles x all MT m-tiles per supergroup.
// Epilogue: LDS-bounce transposed coalesced stores.
// ---------------------------------------------------------------------------
__global__ __launch_bounds__(256) void gemm3m(
    const float* __restrict__ Af32,
    const u16* __restrict__ Ahi, const u16* __restrict__ Alo,
    const u16* __restrict__ Whi, const u16* __restrict__ Wlo,
    const float* __restrict__ bias,
    float* __restrict__ C,
    int Nreal, int Kreal, int Kp, int lda, int ldc, int amode,
    int MT, int NSUB)
{
    extern __shared__ __align__(16) char smem[];
    u16 (*As)[128][32] = (u16 (*)[128][32])smem;            // [2][128][32]
    u16 (*Ws)[128][32] = (u16 (*)[128][32])(smem + 16384);  // [2][128][32]
    float (*Cs)[129]   = (float (*)[129])smem;              // epilogue alias

    const int tid  = threadIdx.x;
    const int lane = tid & 63, wave = tid >> 6;

    const int bid   = blockIdx.x;
    const int super = bid / (NSUB * MT);
    const int rem   = bid - super * (NSUB * MT);
    const int mtile = rem / NSUB;
    const int ntile = super * NSUB + (rem - mtile * NSUB);
    const int m0 = mtile * 128, n0 = ntile * 128;

    const int wm = (wave >> 1) * 64, wn = (wave & 1) * 64;

    f32x4 acc[4][4];
#pragma unroll
    for (int i = 0; i < 4; ++i)
#pragma unroll
        for (int j = 0; j < 4; ++j)
#pragma unroll
            for (int r = 0; r < 4; ++r) acc[i][j][r] = 0.f;

    const int srow = tid >> 2;
    const int sq   = tid & 3;
    const int dq   = (sq ^ ((srow >> 2) & 3)) * 8;
    const int fr   = lane & 15;
    const int fq   = lane >> 4;
    const int rcol = (fq ^ ((fr >> 2) & 3)) * 8;

    // gload_lds assignment (amode 1): one wave per buffer
    const u16* gb = nullptr; u16* lb = nullptr; int gstr = 0;
    if (amode != 0) {
        u16* AsB = (u16*)smem;
        u16* WsB = (u16*)(smem + 16384);
        if (wave == 0)      { gb = Ahi + (size_t)m0 * lda; gstr = lda; lb = AsB; }
        else if (wave == 1) { gb = Alo + (size_t)m0 * lda; gstr = lda; lb = AsB + 4096; }
        else if (wave == 2) { gb = Whi + (size_t)n0 * Kp;  gstr = Kp;  lb = WsB; }
        else                { gb = Wlo + (size_t)n0 * Kp;  gstr = Kp;  lb = WsB + 4096; }
    }
    const int lrow = lane >> 2, lq = lane & 3;

    for (int k0 = 0; k0 < Kp; k0 += 32) {
        if (amode == 0) {
#pragma unroll
            for (int half = 0; half < 2; ++half) {
                int row = half * 64 + srow;
                int kc  = k0 + sq * 8;
                union { u16 s[8]; short8 v; } uh, ul;
                if (kc + 8 <= Kreal) {
                    const float* p = &Af32[(size_t)(m0 + row) * lda + kc];
#pragma unroll
                    for (int j = 0; j < 8; ++j) {
                        float xv = p[j];
                        u16 hh = f32_to_bf16(xv);
                        uh.s[j] = hh;
                        ul.s[j] = f32_to_bf16(xv - bf16_to_f32(hh));
                    }
                } else {
#pragma unroll
                    for (int j = 0; j < 8; ++j) { uh.s[j] = 0; ul.s[j] = 0; }
                }
                *(short8*)&As[0][row][dq] = uh.v;
                *(short8*)&As[1][row][dq] = ul.v;
                size_t wo = (size_t)(n0 + row) * Kp + k0 + sq * 8;
                *(short8*)&Ws[0][row][dq] = *(const short8*)(Whi + wo);
                *(short8*)&Ws[1][row][dq] = *(const short8*)(Wlo + wo);
            }
        } else {
            // 8 x 1KB async stages per wave; LDS linear, source pre-swizzled
#pragma unroll
            for (int g = 0; g < 8; ++g) {
                int row = g * 16 + lrow;
                int srcq = lq ^ ((row >> 2) & 3);
                gload16(gb + (size_t)row * gstr + k0 + srcq * 8, lb + g * 512);
            }
        }
        __syncthreads();

        short8 ah[4], al[4], wh[4], wl[4];
#pragma unroll
        for (int f = 0; f < 4; ++f) {
            int arow = wm + f * 16 + fr;
            ah[f] = *(const short8*)&As[0][arow][rcol];
            al[f] = *(const short8*)&As[1][arow][rcol];
            int wrow = wn + f * 16 + fr;
            wh[f] = *(const short8*)&Ws[0][wrow][rcol];
            wl[f] = *(const short8*)&Ws[1][wrow][rcol];
        }
#pragma unroll
        for (int i = 0; i < 4; ++i)
#pragma unroll
            for (int j = 0; j < 4; ++j) {
                acc[i][j] = __builtin_amdgcn_mfma_f32_16x16x32_bf16(ah[i], wh[j], acc[i][j], 0, 0, 0);
                acc[i][j] = __builtin_amdgcn_mfma_f32_16x16x32_bf16(ah[i], wl[j], acc[i][j], 0, 0, 0);
                acc[i][j] = __builtin_amdgcn_mfma_f32_16x16x32_bf16(al[i], wh[j], acc[i][j], 0, 0, 0);
            }
        __syncthreads();
    }

    // ---- coalesced epilogue via LDS bounce ----
    const int erow = tid & 31;
    const int echk = tid >> 5;
    const int gm_base = m0 + ((erow >> 4) * 64) + (erow & 15);
    const int gn0 = n0 + echk * 16;
    const bool vec4ok = ((ldc & 3) == 0);

#pragma unroll
    for (int i = 0; i < 4; ++i) {
        __syncthreads();
#pragma unroll
        for (int j = 0; j < 4; ++j)
#pragma unroll
            for (int r = 0; r < 4; ++r)
                Cs[(wave >> 1) * 16 + fq * 4 + r][wn + j * 16 + fr] = acc[i][j][r];
        __syncthreads();

        const int gm = gm_base + i * 16;
        float* crow = C + (size_t)gm * ldc;
        if (gn0 + 16 <= Nreal) {
#pragma unroll
            for (int q = 0; q < 4; ++q) {
                f32x4 v = *(const f32x4*)&Cs[erow][echk * 16 + q * 4];
                if (bias) {
                    f32x4 bv = *(const f32x4*)&bias[gn0 + q * 4];
                    v += bv;
                }
                if (vec4ok) {
                    *(f32x4*)&crow[gn0 + q * 4] = v;
                } else {
                    f32x2 lo2 = {v[0], v[1]}, hi2 = {v[2], v[3]};
                    *(f32x2*)&crow[gn0 + q * 4]     = lo2;
                    *(f32x2*)&crow[gn0 + q * 4 + 2] = hi2;
                }
            }
        } else {
#pragma unroll
            for (int q = 0; q < 4; ++q)
#pragma unroll
                for (int p = 0; p < 4; ++p) {
                    int n = gn0 + q * 4 + p;
                    if (n < Nreal)
                        crow[n] = Cs[erow][echk * 16 + q * 4 + p] + (bias ? bias[n] : 0.f);
                }
        }
    }
}

// ---------------------------------------------------------------------------
// Persistent LSTM, 64 timesteps per launch. W slice (32 gate-cols, hi+lo) in
// LDS (XOR-swizzled). Depth-6 pipelined k-loop. h cross-block transport:
// packed u32 (hi|lo) written via agent-scope write-through atomic stores ->
// visible at L3 once vmcnt drains (no wbl2, no fences). Barrier: per-block
// monotonic flag store + per-thread parallel polling (no RMW, no tag-walks).
// Consumers read packed h with normal cached loads (L2-shared per XCD) and
// unpack via v_perm_b32.
// ---------------------------------------------------------------------------
#define PF(S, KT_) do {                                                        \
    int q_ = (((KT_) * 4 + fq) ^ sxor) * 8;                                    \
    a0h_##S = *(const short8*)&Wlds[rA * Kp + q_];                             \
    a0l_##S = *(const short8*)&Wlds[(32 + rA) * Kp + q_];                      \
    a1h_##S = *(const short8*)&Wlds[rB * Kp + q_];                             \
    a1l_##S = *(const short8*)&Wlds[(32 + rB) * Kp + q_];                      \
    u32x4 u0_ = *(const u32x4*)(hrow + (KT_) * 32 + fq * 8);                   \
    u32x4 u1_ = *(const u32x4*)(hrow + (KT_) * 32 + fq * 8 + 4);               \
    union { short8 v; u32 d[4]; } H_, L_;                                      \
    H_.d[0] = __builtin_amdgcn_perm(u0_[1], u0_[0], 0x05040100u);              \
    L_.d[0] = __builtin_amdgcn_perm(u0_[1], u0_[0], 0x07060302u);              \
    H_.d[1] = __builtin_amdgcn_perm(u0_[3], u0_[2], 0x05040100u);              \
    L_.d[1] = __builtin_amdgcn_perm(u0_[3], u0_[2], 0x07060302u);              \
    H_.d[2] = __builtin_amdgcn_perm(u1_[1], u1_[0], 0x05040100u);              \
    L_.d[2] = __builtin_amdgcn_perm(u1_[1], u1_[0], 0x07060302u);              \
    H_.d[3] = __builtin_amdgcn_perm(u1_[3], u1_[2], 0x05040100u);              \
    L_.d[3] = __builtin_amdgcn_perm(u1_[3], u1_[2], 0x07060302u);              \
    hh_##S = H_.v; hl_##S = L_.v;                                              \
} while (0)

#define CM(S) do {                                                             \
    accA = __builtin_amdgcn_mfma_f32_16x16x32_bf16(a0h_##S, hh_##S, accA, 0, 0, 0); \
    accB = __builtin_amdgcn_mfma_f32_16x16x32_bf16(a1h_##S, hh_##S, accB, 0, 0, 0); \
    accA = __builtin_amdgcn_mfma_f32_16x16x32_bf16(a0h_##S, hl_##S, accA, 0, 0, 0); \
    accB = __builtin_amdgcn_mfma_f32_16x16x32_bf16(a1h_##S, hl_##S, accB, 0, 0, 0); \
    accA = __builtin_amdgcn_mfma_f32_16x16x32_bf16(a0l_##S, hh_##S, accA, 0, 0, 0); \
    accB = __builtin_amdgcn_mfma_f32_16x16x32_bf16(a1l_##S, hh_##S, accB, 0, 0, 0); \
} while (0)

__global__ __launch_bounds__(256, 1) void persistent_lstm(
    const u16* __restrict__ Whi, const u16* __restrict__ Wlo,   // [N4][Kp]
    const u32* __restrict__ h0HL,                               // [64][Kp]
    u32* __restrict__ seqHL,                                    // [T*64][Kp]
    u16* __restrict__ seqHi, u16* __restrict__ seqLo,           // [T*64][Kp]
    const float* __restrict__ pre,                              // [64*64][N4]
    const float* __restrict__ c_in, float* __restrict__ c_out,  // [64][dout]
    int* __restrict__ flags,                                    // [G] monotonic
    int t0, int N4, int Kp, int dout, int G)
{
    extern __shared__ __align__(16) u16 Wlds[];   // [2][32][Kp] swizzled
    const int tid  = threadIdx.x;
    const int lane = tid & 63, wave = tid >> 6;
    const int fr = lane & 15, fq = lane >> 4;
    const int c0blk = blockIdx.x * 32;
    const int CH = Kp >> 3;
    const int b = wave * 16 + fr;

    // stage W slice into LDS, chunk slot = q ^ (row&7)
    for (int idx = tid; idx < 64 * CH; idx += 256) {
        int buf = idx / (32 * CH);
        int rem = idx - buf * 32 * CH;
        int r = rem / CH, q = rem - r * CH;
        const u16* src = buf ? Wlo : Whi;
        short8 v = *(const short8*)(src + (size_t)(c0blk + r) * Kp + q * 8);
        *(short8*)&Wlds[(buf * 32 + r) * Kp + (q ^ (r & 7)) * 8] = v;
    }

    const int cA = c0blk + fq * 4;
    const int cB = cA + 16;
    const int jA = cA >> 2, jB = cB >> 2;
    float cregA = c_in[(size_t)b * dout + jA];
    float cregB = c_in[(size_t)b * dout + jB];

    const int rA = fr, rB = 16 + fr;
    const int sxor = fr & 7;
    const int KT = Kp >> 5;            // multiple of 6 by construction

    f32x4 preA = *(const f32x4*)(pre + (size_t)b * N4 + cA);
    f32x4 preB = *(const f32x4*)(pre + (size_t)b * N4 + cB);
    __syncthreads();

    for (int ts = 0; ts < 64; ++ts) {
        const int t = t0 + ts;
        const u32* hbase = (t == 0) ? h0HL : seqHL + (size_t)(t - 1) * 64 * Kp;
        const u32* hrow = hbase + (size_t)b * Kp;

        f32x4 accA = {0.f, 0.f, 0.f, 0.f};
        f32x4 accB = {0.f, 0.f, 0.f, 0.f};
        short8 a0h_0, a0l_0, a1h_0, a1l_0, hh_0, hl_0;
        short8 a0h_1, a0l_1, a1h_1, a1l_1, hh_1, hl_1;
        short8 a0h_2, a0l_2, a1h_2, a1l_2, hh_2, hl_2;
        short8 a0h_3, a0l_3, a1h_3, a1l_3, hh_3, hl_3;
        short8 a0h_4, a0l_4, a1h_4, a1l_4, hh_4, hl_4;
        short8 a0h_5, a0l_5, a1h_5, a1l_5, hh_5, hl_5;

        PF(0, 0); PF(1, 1); PF(2, 2); PF(3, 3); PF(4, 4); PF(5, 5);
        for (int kt = 0; kt < KT - 6; kt += 6) {
            CM(0); PF(0, kt + 6);
            CM(1); PF(1, kt + 7);
            CM(2); PF(2, kt + 8);
            CM(3); PF(3, kt + 9);
            CM(4); PF(4, kt + 10);
            CM(5); PF(5, kt + 11);
        }
        CM(0); CM(1); CM(2); CM(3); CM(4); CM(5);

        // epilogue: gates -> c,h ; write h packed (write-through) + plain
#pragma unroll
        for (int ct = 0; ct < 2; ++ct) {
            f32x4 a = ct ? accB : accA;
            f32x4 p = ct ? preB : preA;
            int j  = ct ? jB : jA;
            float gi = a[0] + p[0];
            float gf = a[1] + p[1];
            float gg = a[2] + p[2];
            float go_ = a[3] + p[3];
            float si = 1.f / (1.f + expf(-gi));
            float sf = 1.f / (1.f + expf(-gf));
            float so = 1.f / (1.f + expf(-go_));
            float tg = tanhf(gg);
            float cn = sf * (ct ? cregB : cregA) + si * tg;
            float hv = so * tanhf(cn);
            if (ct) cregB = cn; else cregA = cn;
            u16 hb = f32_to_bf16(hv);
            u16 lb = f32_to_bf16(hv - bf16_to_f32(hb));
            __hip_atomic_store(&seqHL[(size_t)(t * 64 + b) * Kp + j],
                               (u32)hb | ((u32)lb << 16),
                               __ATOMIC_RELAXED, __HIP_MEMORY_SCOPE_AGENT);
            size_t so_ = (size_t)(t * 64 + b) * Kp + j;
            seqHi[so_] = hb;
            seqLo[so_] = lb;
        }

        if (ts != 63) {
            __syncthreads();   // drains vmcnt: packed h already acked at L3
            // prefetch next-step pre while flags settle
            {
                const float* prow2 = pre + (size_t)((ts + 1) * 64 + b) * N4;
                preA = *(const f32x4*)(prow2 + cA);
                preB = *(const f32x4*)(prow2 + cB);
            }
            if (tid == 0)
                __hip_atomic_store(&flags[blockIdx.x], ts + 1,
                                   __ATOMIC_RELAXED, __HIP_MEMORY_SCOPE_AGENT);
            if (tid < G) {
                while (__hip_atomic_load(&flags[tid], __ATOMIC_RELAXED,
                                         __HIP_MEMORY_SCOPE_AGENT) < ts + 1)
                    __builtin_amdgcn_s_sleep(1);
            }
            __syncthreads();
            __builtin_amdgcn_sched_barrier(0);
        }
    }

    c_out[(size_t)b * dout + jA] = cregA;
    c_out[(size_t)b * dout + jB] = cregB;
}

// ---------------------------------------------------------------------------
extern "C" void kernel_launch(void* const* d_in, const int* in_sizes, int n_in,
                              void* d_out, int out_size, void* d_ws, size_t ws_size,
                              hipStream_t stream)
{
    const int T = 128, B = 64, EMB = 400, HID = 1152, NTOK = 33278;
    const int TB = T * B;

    const float* x     = (const float*)d_in[0];
    const float* h0[3] = {(const float*)d_in[1], (const float*)d_in[2], (const float*)d_in[3]};
    const float* c0[3] = {(const float*)d_in[4], (const float*)d_in[5], (const float*)d_in[6]};
    const float* W_ih[3] = {(const float*)d_in[7],  (const float*)d_in[11], (const float*)d_in[15]};
    const float* W_hh[3] = {(const float*)d_in[8],  (const float*)d_in[12], (const float*)d_in[16]};
    const float* b_ih[3] = {(const float*)d_in[9],  (const float*)d_in[13], (const float*)d_in[17]};
    const float* b_hh[3] = {(const float*)d_in[10], (const float*)d_in[14], (const float*)d_in[18]};
    const float* W_dec = (const float*)d_in[19];
    const float* b_dec = (const float*)d_in[20];

    const int din[3]    = {EMB, HID, HID};     // input dim per layer
    const int Kpre[3]   = {416, 1152, 1152};   // padded K of pre-GEMM
    const int dh[3]     = {HID, HID, EMB};     // hidden dim per layer
    const int KpH[3]    = {1152, 1152, 576};   // padded h width (KT%6==0)
    const int N4[3]     = {4608, 4608, 1600};
    const int N4p128[3] = {4608, 4608, 1664};
    const int NSUBpre[3] = {6, 6, 13};         // supergroup n-tiles
    const int Gp[3]     = {144, 144, 50};      // persistent grid (N4/32)

    char* wsp = (char*)d_ws;
    size_t off = 0;
    auto alloc = [&](size_t bytes) -> char* {
        char* p = wsp + off; off = (off + bytes + 255) & ~(size_t)255; return p;
    };

    float* pre   = (float*)alloc((size_t)4096 * 4608 * 4);        // 75.5 MB (half T)
    u16* seqHi   = (u16*)alloc((size_t)TB * 1152 * 2);            // 18.9 MB
    u16* seqLo   = (u16*)alloc((size_t)TB * 1152 * 2);            // 18.9 MB
    u32* seqHL   = (u32*)alloc((size_t)TB * 1152 * 4);            // 37.7 MB
    u16* WihHi   = (u16*)alloc((size_t)4608 * 1152 * 2);          // 10.6 MB
    u16* WihLo   = (u16*)alloc((size_t)4608 * 1152 * 2);
    u16* WhhHi   = (u16*)alloc((size_t)4608 * 1152 * 2);
    u16* WhhLo   = (u16*)alloc((size_t)4608 * 1152 * 2);
    u32* h0HL    = (u32*)alloc((size_t)B * 1152 * 4);
    float* bsum  = (float*)alloc(4608 * 4);
    float* cstb  = (float*)alloc((size_t)B * HID * 4);
    int* flags   = (int*)alloc(6 * 256 * 4);                      // per-launch flag arrays
    // decoder W split aliases pre (pre dead by then): 2 x 27.7 MB <= 75.5 MB
    u16* WdecHi  = (u16*)pre;
    u16* WdecLo  = (u16*)pre + (size_t)33280 * 416;

    hipMemsetAsync(flags, 0, 6 * 256 * 4, stream);
    hipFuncSetAttribute(reinterpret_cast<const void*>(persistent_lstm),
                        hipFuncAttributeMaxDynamicSharedMemorySize, 160 * 1024);
    hipFuncSetAttribute(reinterpret_cast<const void*>(gemm3m),
                        hipFuncAttributeMaxDynamicSharedMemorySize, 64 * 1024);

    auto run_split = [&](const float* src, u16* hi, u16* lo,
                         int N, int K, int Npad, int Kpad, int perm) {
        int total = Npad * Kpad;
        split_pad_kernel<<<(total + 255) / 256, 256, 0, stream>>>(
            src, hi, lo, N, K, Npad, Kpad, perm);
    };

    for (int l = 0; l < 3; ++l) {
        run_split(W_hh[l], WhhHi, WhhLo, N4[l], dh[l], N4[l], KpH[l], 1);
        pack_h0_kernel<<<(B * KpH[l] + 255) / 256, 256, 0, stream>>>(
            h0[l], h0HL, B, dh[l], KpH[l]);
        run_split(W_ih[l], WihHi, WihLo, N4[l], din[l], N4p128[l], Kpre[l], 1);
        bias_perm_kernel<<<(N4[l] + 255) / 256, 256, 0, stream>>>(
            b_ih[l], b_hh[l], bsum, N4[l]);

        const int ldaA = (l == 0) ? EMB : KpH[l - 1];
        const int NT = N4p128[l] / 128, MT = 32;
        const size_t ldsB = (size_t)128 * KpH[l];   // 2*32*Kp*2 bytes

        for (int halfT = 0; halfT < 2; ++halfT) {
            const int li = l * 2 + halfT;
            const float* Af32 = (l == 0) ? (x + (size_t)halfT * 4096 * EMB) : nullptr;
            const u16* Ah = (l == 0) ? nullptr : (seqHi + (size_t)halfT * 4096 * ldaA);
            const u16* Al = (l == 0) ? nullptr : (seqLo + (size_t)halfT * 4096 * ldaA);
            gemm3m<<<dim3(NT * MT), 256, 32768, stream>>>(
                Af32, Ah, Al, WihHi, WihLo, bsum, pre,
                N4[l], din[l], Kpre[l], ldaA, N4[l], (l == 0) ? 0 : 1,
                MT, NSUBpre[l]);

            const float* cin = (halfT == 0) ? c0[l] : cstb;
            persistent_lstm<<<dim3(Gp[l]), 256, ldsB, stream>>>(
                WhhHi, WhhLo, h0HL, seqHL, seqHi, seqLo, pre,
                cin, cstb, flags + li * 256,
                halfT * 64, N4[l], KpH[l], dh[l], Gp[l]);
        }
    }

    // decoder: out = H2 @ W_dec^T + b_dec   (A stride 576, K extent 416)
    run_split(W_dec, WdecHi, WdecLo, NTOK, EMB, 33280, 416, 0);
    gemm3m<<<dim3(260 * 64), 256, 32768, stream>>>(
        nullptr, seqHi, seqLo, WdecHi, WdecLo, b_dec, (float*)d_out,
        NTOK, EMB, 416, 576, NTOK, 1,
        64, 13);
}

// Round 7
// 6753.942 us; speedup vs baseline: 1.0361x; 1.0361x over previous
//
#include <hip/hip_runtime.h>
#include <math.h>

typedef unsigned short u16;
typedef unsigned int u32;
typedef __attribute__((ext_vector_type(8))) short short8;
typedef __attribute__((ext_vector_type(4))) float f32x4;
typedef __attribute__((ext_vector_type(2))) float f32x2;

__device__ __forceinline__ u16 f32_to_bf16(float x) {
    union { float f; unsigned int u; } v; v.f = x;
    unsigned int u = v.u;
    return (u16)((u + 0x7FFFu + ((u >> 16) & 1u)) >> 16);
}
__device__ __forceinline__ float bf16_to_f32(u16 h) {
    union { unsigned int u; float f; } v; v.u = ((unsigned int)h) << 16; return v.f;
}

// async global->LDS, 16B per lane; LDS dest is wave-uniform base + lane*16
__device__ __forceinline__ void gload16(const u16* g, u16* l) {
    __builtin_amdgcn_global_load_lds(
        (const __attribute__((address_space(1))) void*)g,
        (__attribute__((address_space(3))) void*)l, 16, 0, 0);
}

// ---------------------------------------------------------------------------
// split fp32 [N][K] (optionally gate-permuted rows) -> bf16 hi/lo [Npad][Kpad]
// perm=1: source row for dst row n is (n&3)*(N/4) + (n>>2)   (c = j*4+g)
// ---------------------------------------------------------------------------
__global__ void split_pad_kernel(const float* __restrict__ src,
                                 u16* __restrict__ hi, u16* __restrict__ lo,
                                 int N, int K, int Npad, int Kpad, int perm)
{
    int idx = blockIdx.x * 256 + threadIdx.x;
    if (idx >= Npad * Kpad) return;
    int n = idx / Kpad, k = idx - n * Kpad;
    float x = 0.f;
    if (n < N && k < K) {
        int srow = n;
        if (perm) { int dout = N >> 2; srow = (n & 3) * dout + (n >> 2); }
        x = src[(size_t)srow * K + k];
    }
    u16 h = f32_to_bf16(x);
    hi[idx] = h;
    lo[idx] = f32_to_bf16(x - bf16_to_f32(h));
}

__global__ void bias_perm_kernel(const float* __restrict__ bi,
                                 const float* __restrict__ bh,
                                 float* __restrict__ out, int N4)
{
    int c = blockIdx.x * 256 + threadIdx.x;
    if (c >= N4) return;
    int dout = N4 >> 2;
    int s = (c & 3) * dout + (c >> 2);
    out[c] = bi[s] + bh[s];
}

// ---------------------------------------------------------------------------
// C[M][ldc] = A @ W^T + bias, bf16x3 MFMA. M = 8192 fixed (64 m-tiles).
// Grid = NT*64, 1-D. XCD-chunked mapping (round-robin dispatch assumed):
//   chunk = bid & 7 (the XCD), c = bid >> 3, ntile = c >> 3,
//   mtile = chunk*8 + (c & 7).
// Each XCD owns 8 m-tiles x all n-tiles: A-panel (~1.7 MB) L2-resident,
// each W-tile fetched once per XCD and shared by its 8 m-blocks.
// amode 0: Af32 fp32 split on the fly. amode 1: global_load_lds staging
// (linear LDS dest, inverse-XOR pre-swizzled global source).
// Epilogue: LDS-bounce transposed coalesced stores.
// ---------------------------------------------------------------------------
__global__ __launch_bounds__(256) void gemm3m(
    const float* __restrict__ Af32,
    const u16* __restrict__ Ahi, const u16* __restrict__ Alo,
    const u16* __restrict__ Whi, const u16* __restrict__ Wlo,
    const float* __restrict__ bias,
    float* __restrict__ C,
    int Nreal, int Kreal, int Kp, int lda, int ldc, int amode)
{
    extern __shared__ __align__(16) char smem[];
    u16 (*As)[128][32] = (u16 (*)[128][32])smem;            // [2][128][32]
    u16 (*Ws)[128][32] = (u16 (*)[128][32])(smem + 16384);  // [2][128][32]
    float (*Cs)[129]   = (float (*)[129])smem;              // epilogue alias

    const int tid  = threadIdx.x;
    const int lane = tid & 63, wave = tid >> 6;

    const int bid   = blockIdx.x;
    const int chunk = bid & 7;
    const int c     = bid >> 3;
    const int ntile = c >> 3;
    const int mtile = (chunk << 3) | (c & 7);
    const int m0 = mtile * 128, n0 = ntile * 128;

    const int wm = (wave >> 1) * 64, wn = (wave & 1) * 64;

    f32x4 acc[4][4];
#pragma unroll
    for (int i = 0; i < 4; ++i)
#pragma unroll
        for (int j = 0; j < 4; ++j)
#pragma unroll
            for (int r = 0; r < 4; ++r) acc[i][j][r] = 0.f;

    const int srow = tid >> 2;
    const int sq   = tid & 3;
    const int dq   = (sq ^ ((srow >> 2) & 3)) * 8;
    const int fr   = lane & 15;
    const int fq   = lane >> 4;
    const int rcol = (fq ^ ((fr >> 2) & 3)) * 8;

    // gload_lds assignment (amode 1): one wave per buffer
    const u16* gb = nullptr; u16* lb = nullptr; int gstr = 0;
    if (amode != 0) {
        u16* AsB = (u16*)smem;
        u16* WsB = (u16*)(smem + 16384);
        if (wave == 0)      { gb = Ahi + (size_t)m0 * lda; gstr = lda; lb = AsB; }
        else if (wave == 1) { gb = Alo + (size_t)m0 * lda; gstr = lda; lb = AsB + 4096; }
        else if (wave == 2) { gb = Whi + (size_t)n0 * Kp;  gstr = Kp;  lb = WsB; }
        else                { gb = Wlo + (size_t)n0 * Kp;  gstr = Kp;  lb = WsB + 4096; }
    }
    const int lrow = lane >> 2, lq = lane & 3;

    for (int k0 = 0; k0 < Kp; k0 += 32) {
        if (amode == 0) {
#pragma unroll
            for (int half = 0; half < 2; ++half) {
                int row = half * 64 + srow;
                int kc  = k0 + sq * 8;
                union { u16 s[8]; short8 v; } uh, ul;
                if (kc + 8 <= Kreal) {
                    const float* p = &Af32[(size_t)(m0 + row) * lda + kc];
#pragma unroll
                    for (int j = 0; j < 8; ++j) {
                        float xv = p[j];
                        u16 hh = f32_to_bf16(xv);
                        uh.s[j] = hh;
                        ul.s[j] = f32_to_bf16(xv - bf16_to_f32(hh));
                    }
                } else {
#pragma unroll
                    for (int j = 0; j < 8; ++j) { uh.s[j] = 0; ul.s[j] = 0; }
                }
                *(short8*)&As[0][row][dq] = uh.v;
                *(short8*)&As[1][row][dq] = ul.v;
                size_t wo = (size_t)(n0 + row) * Kp + k0 + sq * 8;
                *(short8*)&Ws[0][row][dq] = *(const short8*)(Whi + wo);
                *(short8*)&Ws[1][row][dq] = *(const short8*)(Wlo + wo);
            }
        } else {
            // 8 x 1KB async stages per wave; LDS linear, source pre-swizzled
#pragma unroll
            for (int g = 0; g < 8; ++g) {
                int row = g * 16 + lrow;
                int srcq = lq ^ ((row >> 2) & 3);
                gload16(gb + (size_t)row * gstr + k0 + srcq * 8, lb + g * 512);
            }
        }
        __syncthreads();

        short8 ah[4], al[4], wh[4], wl[4];
#pragma unroll
        for (int f = 0; f < 4; ++f) {
            int arow = wm + f * 16 + fr;
            ah[f] = *(const short8*)&As[0][arow][rcol];
            al[f] = *(const short8*)&As[1][arow][rcol];
            int wrow = wn + f * 16 + fr;
            wh[f] = *(const short8*)&Ws[0][wrow][rcol];
            wl[f] = *(const short8*)&Ws[1][wrow][rcol];
        }
#pragma unroll
        for (int i = 0; i < 4; ++i)
#pragma unroll
            for (int j = 0; j < 4; ++j) {
                acc[i][j] = __builtin_amdgcn_mfma_f32_16x16x32_bf16(ah[i], wh[j], acc[i][j], 0, 0, 0);
                acc[i][j] = __builtin_amdgcn_mfma_f32_16x16x32_bf16(ah[i], wl[j], acc[i][j], 0, 0, 0);
                acc[i][j] = __builtin_amdgcn_mfma_f32_16x16x32_bf16(al[i], wh[j], acc[i][j], 0, 0, 0);
            }
        __syncthreads();
    }

    // ---- coalesced epilogue via LDS bounce ----
    const int erow = tid & 31;
    const int echk = tid >> 5;
    const int gm_base = m0 + ((erow >> 4) * 64) + (erow & 15);
    const int gn0 = n0 + echk * 16;
    const bool vec4ok = ((ldc & 3) == 0);

#pragma unroll
    for (int i = 0; i < 4; ++i) {
        __syncthreads();
#pragma unroll
        for (int j = 0; j < 4; ++j)
#pragma unroll
            for (int r = 0; r < 4; ++r)
                Cs[(wave >> 1) * 16 + fq * 4 + r][wn + j * 16 + fr] = acc[i][j][r];
        __syncthreads();

        const int gm = gm_base + i * 16;
        float* crow = C + (size_t)gm * ldc;
        if (gn0 + 16 <= Nreal) {
#pragma unroll
            for (int q = 0; q < 4; ++q) {
                f32x4 v = *(const f32x4*)&Cs[erow][echk * 16 + q * 4];
                if (bias) {
                    f32x4 bv = *(const f32x4*)&bias[gn0 + q * 4];
                    v += bv;
                }
                if (vec4ok) {
                    *(f32x4*)&crow[gn0 + q * 4] = v;
                } else {
                    f32x2 lo2 = {v[0], v[1]}, hi2 = {v[2], v[3]};
                    *(f32x2*)&crow[gn0 + q * 4]     = lo2;
                    *(f32x2*)&crow[gn0 + q * 4 + 2] = hi2;
                }
            }
        } else {
#pragma unroll
            for (int q = 0; q < 4; ++q)
#pragma unroll
                for (int p = 0; p < 4; ++p) {
                    int n = gn0 + q * 4 + p;
                    if (n < Nreal)
                        crow[n] = Cs[erow][echk * 16 + q * 4 + p] + (bias ? bias[n] : 0.f);
                }
        }
    }
}

// ---------------------------------------------------------------------------
// Persistent LSTM, full T=128 steps in one launch. W slice (32 gate-cols,
// hi+lo) in LDS (XOR-swizzled). Depth-6 pipelined k-loop. h transport: plain
// hi/lo stores + one release-wbl2 per step. Barrier: per-block monotonic flag
// store + per-thread parallel poll (no RMW, no acquire-invalidate -- h lines
// for step t are address-cold in consumer L2s; release guarantees L3).
// ---------------------------------------------------------------------------
#define PF(S, KT_) do {                                                        \
    int q_ = (((KT_) * 4 + fq) ^ sxor) * 8;                                    \
    a0h_##S = *(const short8*)&Wlds[rA * Kp + q_];                             \
    a0l_##S = *(const short8*)&Wlds[(32 + rA) * Kp + q_];                      \
    a1h_##S = *(const short8*)&Wlds[rB * Kp + q_];                             \
    a1l_##S = *(const short8*)&Wlds[(32 + rB) * Kp + q_];                      \
    hh_##S = *(const short8*)(hrow_hi + (KT_) * 32 + fq * 8);                  \
    hl_##S = *(const short8*)(hrow_lo + (KT_) * 32 + fq * 8);                  \
} while (0)

#define CM(S) do {                                                             \
    accA = __builtin_amdgcn_mfma_f32_16x16x32_bf16(a0h_##S, hh_##S, accA, 0, 0, 0); \
    accB = __builtin_amdgcn_mfma_f32_16x16x32_bf16(a1h_##S, hh_##S, accB, 0, 0, 0); \
    accA = __builtin_amdgcn_mfma_f32_16x16x32_bf16(a0h_##S, hl_##S, accA, 0, 0, 0); \
    accB = __builtin_amdgcn_mfma_f32_16x16x32_bf16(a1h_##S, hl_##S, accB, 0, 0, 0); \
    accA = __builtin_amdgcn_mfma_f32_16x16x32_bf16(a0l_##S, hh_##S, accA, 0, 0, 0); \
    accB = __builtin_amdgcn_mfma_f32_16x16x32_bf16(a1l_##S, hh_##S, accB, 0, 0, 0); \
} while (0)

__global__ __launch_bounds__(256, 1) void persistent_lstm(
    const u16* __restrict__ Whi, const u16* __restrict__ Wlo,   // [N4][Kp]
    const u16* __restrict__ h0hi, const u16* __restrict__ h0lo, // [64][Kp]
    u16* __restrict__ seqHi, u16* __restrict__ seqLo,           // [T*64][Kp]
    const float* __restrict__ pre,                              // [T*64][N4]
    const float* __restrict__ c_in, float* __restrict__ c_out,  // [64][dout]
    int* __restrict__ flags,                                    // [G] monotonic
    int N4, int Kp, int dout, int G, int TSTEPS)
{
    extern __shared__ __align__(16) u16 Wlds[];   // [2][32][Kp] swizzled
    const int tid  = threadIdx.x;
    const int lane = tid & 63, wave = tid >> 6;
    const int fr = lane & 15, fq = lane >> 4;
    const int c0blk = blockIdx.x * 32;
    const int CH = Kp >> 3;
    const int b = wave * 16 + fr;

    // stage W slice into LDS, chunk slot = q ^ (row&7)
    for (int idx = tid; idx < 64 * CH; idx += 256) {
        int buf = idx / (32 * CH);
        int rem = idx - buf * 32 * CH;
        int r = rem / CH, q = rem - r * CH;
        const u16* src = buf ? Wlo : Whi;
        short8 v = *(const short8*)(src + (size_t)(c0blk + r) * Kp + q * 8);
        *(short8*)&Wlds[(buf * 32 + r) * Kp + (q ^ (r & 7)) * 8] = v;
    }

    const int cA = c0blk + fq * 4;
    const int cB = cA + 16;
    const int jA = cA >> 2, jB = cB >> 2;
    float cregA = c_in[(size_t)b * dout + jA];
    float cregB = c_in[(size_t)b * dout + jB];

    const int rA = fr, rB = 16 + fr;
    const int sxor = fr & 7;
    const int KT = Kp >> 5;            // multiple of 6 by construction

    f32x4 preA = *(const f32x4*)(pre + (size_t)b * N4 + cA);
    f32x4 preB = *(const f32x4*)(pre + (size_t)b * N4 + cB);
    __syncthreads();

    for (int ts = 0; ts < TSTEPS; ++ts) {
        const u16* hbase_hi = (ts == 0) ? h0hi : seqHi + (size_t)(ts - 1) * 64 * Kp;
        const u16* hbase_lo = (ts == 0) ? h0lo : seqLo + (size_t)(ts - 1) * 64 * Kp;
        const u16* hrow_hi = hbase_hi + (size_t)b * Kp;
        const u16* hrow_lo = hbase_lo + (size_t)b * Kp;

        f32x4 accA = {0.f, 0.f, 0.f, 0.f};
        f32x4 accB = {0.f, 0.f, 0.f, 0.f};
        short8 a0h_0, a0l_0, a1h_0, a1l_0, hh_0, hl_0;
        short8 a0h_1, a0l_1, a1h_1, a1l_1, hh_1, hl_1;
        short8 a0h_2, a0l_2, a1h_2, a1l_2, hh_2, hl_2;
        short8 a0h_3, a0l_3, a1h_3, a1l_3, hh_3, hl_3;
        short8 a0h_4, a0l_4, a1h_4, a1l_4, hh_4, hl_4;
        short8 a0h_5, a0l_5, a1h_5, a1l_5, hh_5, hl_5;

        PF(0, 0); PF(1, 1); PF(2, 2); PF(3, 3); PF(4, 4); PF(5, 5);
        for (int kt = 0; kt < KT - 6; kt += 6) {
            CM(0); PF(0, kt + 6);
            CM(1); PF(1, kt + 7);
            CM(2); PF(2, kt + 8);
            CM(3); PF(3, kt + 9);
            CM(4); PF(4, kt + 10);
            CM(5); PF(5, kt + 11);
        }
        CM(0); CM(1); CM(2); CM(3); CM(4); CM(5);

        // epilogue: gates -> c,h ; write h (hi/lo)
#pragma unroll
        for (int ct = 0; ct < 2; ++ct) {
            f32x4 a = ct ? accB : accA;
            f32x4 p = ct ? preB : preA;
            int j  = ct ? jB : jA;
            float gi = a[0] + p[0];
            float gf = a[1] + p[1];
            float gg = a[2] + p[2];
            float go_ = a[3] + p[3];
            float si = 1.f / (1.f + expf(-gi));
            float sf = 1.f / (1.f + expf(-gf));
            float so = 1.f / (1.f + expf(-go_));
            float tg = tanhf(gg);
            float cn = sf * (ct ? cregB : cregA) + si * tg;
            float hv = so * tanhf(cn);
            if (ct) cregB = cn; else cregA = cn;
            u16 hb = f32_to_bf16(hv);
            size_t so_ = (size_t)(ts * 64 + b) * Kp + j;
            seqHi[so_] = hb;
            seqLo[so_] = f32_to_bf16(hv - bf16_to_f32(hb));
        }

        if (ts != TSTEPS - 1) {
            __syncthreads();   // drain all waves' h stores to L2
            if (tid == 0) {
                __builtin_amdgcn_fence(__ATOMIC_RELEASE, "agent");   // wbl2
                __hip_atomic_store(&flags[blockIdx.x], ts + 1,
                                   __ATOMIC_RELAXED, __HIP_MEMORY_SCOPE_AGENT);
            }
            // prefetch next-step pre while flags settle
            {
                const float* prow2 = pre + (size_t)((ts + 1) * 64 + b) * N4;
                preA = *(const f32x4*)(prow2 + cA);
                preB = *(const f32x4*)(prow2 + cB);
            }
            if (tid < G) {
                while (__hip_atomic_load(&flags[tid], __ATOMIC_RELAXED,
                                         __HIP_MEMORY_SCOPE_AGENT) < ts + 1)
                    __builtin_amdgcn_s_sleep(1);
            }
            __syncthreads();
            __builtin_amdgcn_sched_barrier(0);
        }
    }

    c_out[(size_t)b * dout + jA] = cregA;
    c_out[(size_t)b * dout + jB] = cregB;
}

// ---------------------------------------------------------------------------
extern "C" void kernel_launch(void* const* d_in, const int* in_sizes, int n_in,
                              void* d_out, int out_size, void* d_ws, size_t ws_size,
                              hipStream_t stream)
{
    const int T = 128, B = 64, EMB = 400, HID = 1152, NTOK = 33278;
    const int TB = T * B;

    const float* x     = (const float*)d_in[0];
    const float* h0[3] = {(const float*)d_in[1], (const float*)d_in[2], (const float*)d_in[3]};
    const float* c0[3] = {(const float*)d_in[4], (const float*)d_in[5], (const float*)d_in[6]};
    const float* W_ih[3] = {(const float*)d_in[7],  (const float*)d_in[11], (const float*)d_in[15]};
    const float* W_hh[3] = {(const float*)d_in[8],  (const float*)d_in[12], (const float*)d_in[16]};
    const float* b_ih[3] = {(const float*)d_in[9],  (const float*)d_in[13], (const float*)d_in[17]};
    const float* b_hh[3] = {(const float*)d_in[10], (const float*)d_in[14], (const float*)d_in[18]};
    const float* W_dec = (const float*)d_in[19];
    const float* b_dec = (const float*)d_in[20];

    const int din[3]    = {EMB, HID, HID};     // input dim per layer
    const int Kpre[3]   = {416, 1152, 1152};   // padded K of pre-GEMM
    const int dh[3]     = {HID, HID, EMB};     // hidden dim per layer
    const int KpH[3]    = {1152, 1152, 576};   // padded h width (KT%6==0)
    const int N4[3]     = {4608, 4608, 1600};
    const int N4p128[3] = {4608, 4608, 1664};
    const int Gp[3]     = {144, 144, 50};      // persistent grid (N4/32)

    char* wsp = (char*)d_ws;
    size_t off = 0;
    auto alloc = [&](size_t bytes) -> char* {
        char* p = wsp + off; off = (off + bytes + 255) & ~(size_t)255; return p;
    };

    float* pre   = (float*)alloc((size_t)TB * 4608 * 4);          // 151 MB (full T)
    u16* seqHi   = (u16*)alloc((size_t)TB * 1152 * 2);            // 18.9 MB
    u16* seqLo   = (u16*)alloc((size_t)TB * 1152 * 2);            // 18.9 MB
    u16* WihHi   = (u16*)alloc((size_t)4608 * 1152 * 2);          // 10.6 MB
    u16* WihLo   = (u16*)alloc((size_t)4608 * 1152 * 2);
    u16* WhhHi   = (u16*)alloc((size_t)4608 * 1152 * 2);
    u16* WhhLo   = (u16*)alloc((size_t)4608 * 1152 * 2);
    u16* h0Hi    = (u16*)alloc((size_t)B * 1152 * 2);
    u16* h0Lo    = (u16*)alloc((size_t)B * 1152 * 2);
    float* bsum  = (float*)alloc(4608 * 4);
    float* cstb  = (float*)alloc((size_t)B * HID * 4);
    int* flags   = (int*)alloc(3 * 256 * 4);
    // decoder W split aliases pre (pre dead by then): 2 x 27.7 MB <= 151 MB
    u16* WdecHi  = (u16*)pre;
    u16* WdecLo  = (u16*)pre + (size_t)33280 * 416;

    hipMemsetAsync(flags, 0, 3 * 256 * 4, stream);
    hipFuncSetAttribute(reinterpret_cast<const void*>(persistent_lstm),
                        hipFuncAttributeMaxDynamicSharedMemorySize, 160 * 1024);
    hipFuncSetAttribute(reinterpret_cast<const void*>(gemm3m),
                        hipFuncAttributeMaxDynamicSharedMemorySize, 64 * 1024);

    auto run_split = [&](const float* src, u16* hi, u16* lo,
                         int N, int K, int Npad, int Kpad, int perm) {
        int total = Npad * Kpad;
        split_pad_kernel<<<(total + 255) / 256, 256, 0, stream>>>(
            src, hi, lo, N, K, Npad, Kpad, perm);
    };

    for (int l = 0; l < 3; ++l) {
        run_split(W_hh[l], WhhHi, WhhLo, N4[l], dh[l], N4[l], KpH[l], 1);
        run_split(h0[l], h0Hi, h0Lo, B, dh[l], B, KpH[l], 0);
        run_split(W_ih[l], WihHi, WihLo, N4[l], din[l], N4p128[l], Kpre[l], 1);
        bias_perm_kernel<<<(N4[l] + 255) / 256, 256, 0, stream>>>(
            b_ih[l], b_hh[l], bsum, N4[l]);

        const int ldaA = (l == 0) ? EMB : KpH[l - 1];
        const int NT = N4p128[l] / 128;
        const size_t ldsB = (size_t)128 * KpH[l];   // 2*32*Kp*2 bytes

        // pre = X_seq @ W_ih^T + b_ih + b_hh  (full T, M = 8192)
        const float* Af32 = (l == 0) ? x : nullptr;
        const u16* Ah = (l == 0) ? nullptr : seqHi;
        const u16* Al = (l == 0) ? nullptr : seqLo;
        gemm3m<<<dim3(NT * 64), 256, 32768, stream>>>(
            Af32, Ah, Al, WihHi, WihLo, bsum, pre,
            N4[l], din[l], Kpre[l], ldaA, N4[l], (l == 0) ? 0 : 1);

        persistent_lstm<<<dim3(Gp[l]), 256, ldsB, stream>>>(
            WhhHi, WhhLo, h0Hi, h0Lo, seqHi, seqLo, pre,
            c0[l], cstb, flags + l * 256,
            N4[l], KpH[l], dh[l], Gp[l], T);
    }

    // decoder: out = H2 @ W_dec^T + b_dec   (A stride 576, K extent 416)
    run_split(W_dec, WdecHi, WdecLo, NTOK, EMB, 33280, 416, 0);
    gemm3m<<<dim3(260 * 64), 256, 32768, stream>>>(
        nullptr, seqHi, seqLo, WdecHi, WdecLo, b_dec, (float*)d_out,
        NTOK, EMB, 416, 576, NTOK, 1);
}

// Round 8
// 6102.120 us; speedup vs baseline: 1.1467x; 1.1068x over previous
//
#include <hip/hip_runtime.h>
#include <math.h>

typedef unsigned short u16;
typedef unsigned int u32;
typedef __attribute__((ext_vector_type(8))) short short8;
typedef __attribute__((ext_vector_type(4))) float f32x4;
typedef __attribute__((ext_vector_type(2))) float f32x2;
typedef __attribute__((ext_vector_type(4))) unsigned int u32x4;

__device__ __forceinline__ u16 f32_to_bf16(float x) {
    union { float f; unsigned int u; } v; v.f = x;
    unsigned int u = v.u;
    return (u16)((u + 0x7FFFu + ((u >> 16) & 1u)) >> 16);
}
__device__ __forceinline__ float bf16_to_f32(u16 h) {
    union { unsigned int u; float f; } v; v.u = ((unsigned int)h) << 16; return v.f;
}

// async global->LDS, 16B per lane; LDS dest = wave-uniform base + lane*16
__device__ __forceinline__ void gload16v(const void* g, void* l) {
    __builtin_amdgcn_global_load_lds(
        (const __attribute__((address_space(1))) void*)g,
        (__attribute__((address_space(3))) void*)l, 16, 0, 0);
}

// unpack 8 packed u32 (hi|lo<<16) -> short8 hi, short8 lo (k-ascending)
__device__ __forceinline__ void unpack8(u32x4 p0, u32x4 p1, short8& hv, short8& lv) {
    union { short8 v; u32 d[4]; } H, L;
    H.d[0] = __builtin_amdgcn_perm(p0[1], p0[0], 0x05040100u);
    L.d[0] = __builtin_amdgcn_perm(p0[1], p0[0], 0x07060302u);
    H.d[1] = __builtin_amdgcn_perm(p0[3], p0[2], 0x05040100u);
    L.d[1] = __builtin_amdgcn_perm(p0[3], p0[2], 0x07060302u);
    H.d[2] = __builtin_amdgcn_perm(p1[1], p1[0], 0x05040100u);
    L.d[2] = __builtin_amdgcn_perm(p1[1], p1[0], 0x07060302u);
    H.d[3] = __builtin_amdgcn_perm(p1[3], p1[2], 0x05040100u);
    L.d[3] = __builtin_amdgcn_perm(p1[3], p1[2], 0x07060302u);
    hv = H.v; lv = L.v;
}

// ---------------------------------------------------------------------------
// split fp32 [N][K] (optionally gate-permuted rows) -> bf16 hi/lo [Npad][Kpad]
// ---------------------------------------------------------------------------
__global__ void split_pad_kernel(const float* __restrict__ src,
                                 u16* __restrict__ hi, u16* __restrict__ lo,
                                 int N, int K, int Npad, int Kpad, int perm)
{
    int idx = blockIdx.x * 256 + threadIdx.x;
    if (idx >= Npad * Kpad) return;
    int n = idx / Kpad, k = idx - n * Kpad;
    float x = 0.f;
    if (n < N && k < K) {
        int srow = n;
        if (perm) { int dout = N >> 2; srow = (n & 3) * dout + (n >> 2); }
        x = src[(size_t)srow * K + k];
    }
    u16 h = f32_to_bf16(x);
    hi[idx] = h;
    lo[idx] = f32_to_bf16(x - bf16_to_f32(h));
}

// pack fp32 [B][K] -> u32 (hi | lo<<16) [B][Kpad]
__global__ void pack_h0_kernel(const float* __restrict__ src, u32* __restrict__ dst,
                               int Brows, int K, int Kpad)
{
    int idx = blockIdx.x * 256 + threadIdx.x;
    if (idx >= Brows * Kpad) return;
    int b = idx / Kpad, k = idx - b * Kpad;
    float x = (k < K) ? src[(size_t)b * K + k] : 0.f;
    u16 h = f32_to_bf16(x);
    u16 l = f32_to_bf16(x - bf16_to_f32(h));
    dst[idx] = (u32)h | ((u32)l << 16);
}

// zero columns [c0,c1) of u32 [rows][ld]
__global__ void zero_cols_kernel(u32* __restrict__ p, int rows, int c0, int c1, int ld)
{
    int w = c1 - c0;
    int idx = blockIdx.x * 256 + threadIdx.x;
    if (idx >= rows * w) return;
    int r = idx / w, c = idx - r * w;
    p[(size_t)r * ld + c0 + c] = 0;
}

__global__ void bias_perm_kernel(const float* __restrict__ bi,
                                 const float* __restrict__ bh,
                                 float* __restrict__ out, int N4)
{
    int c = blockIdx.x * 256 + threadIdx.x;
    if (c >= N4) return;
    int dout = N4 >> 2;
    int s = (c & 3) * dout + (c >> 2);
    out[c] = bi[s] + bh[s];
}

// ---------------------------------------------------------------------------
// C[M][ldc] = A @ W^T + bias, bf16x3 MFMA. M = 8192 fixed (64 m-tiles).
// XCD-chunked mapping: chunk = bid&7 (XCD), ntile = (bid>>3)>>3,
// mtile = chunk*8 + ((bid>>3)&7). Per-XCD A-panel L2-resident; each W-tile
// fetched once per XCD.
// AMODE 0: Af32 fp32, split on the fly (reg-staged ds_write).
// AMODE 2: Apk packed u32 (hi|lo), global_load_lds staging + perm unpack.
// W: pre-split hi/lo, global_load_lds staging (AMODE 2) / reg-staged (0).
// Epilogue: LDS-bounce transposed coalesced stores.
// ---------------------------------------------------------------------------
template<int AMODE>
__global__ __launch_bounds__(256) void gemm3m(
    const float* __restrict__ Af32,
    const u32* __restrict__ Apk,
    const u16* __restrict__ Whi, const u16* __restrict__ Wlo,
    const float* __restrict__ bias,
    float* __restrict__ C,
    int Nreal, int Kreal, int Kp, int lda, int ldc)
{
    extern __shared__ __align__(16) char smem[];
    u16 (*As)[128][32] = (u16 (*)[128][32])smem;            // AMODE 0: [2][128][32] u16
    u32* AsP           = (u32*)smem;                         // AMODE 2: [128][32] u32
    u16 (*Ws)[128][32] = (u16 (*)[128][32])(smem + 16384);  // [2][128][32] u16
    float (*Cs)[129]   = (float (*)[129])smem;              // epilogue alias

    const int tid  = threadIdx.x;
    const int lane = tid & 63, wave = tid >> 6;

    const int bid   = blockIdx.x;
    const int chunk = bid & 7;
    const int c     = bid >> 3;
    const int ntile = c >> 3;
    const int mtile = (chunk << 3) | (c & 7);
    const int m0 = mtile * 128, n0 = ntile * 128;

    const int wm = (wave >> 1) * 64, wn = (wave & 1) * 64;

    f32x4 acc[4][4];
#pragma unroll
    for (int i = 0; i < 4; ++i)
#pragma unroll
        for (int j = 0; j < 4; ++j)
#pragma unroll
            for (int r = 0; r < 4; ++r) acc[i][j][r] = 0.f;

    const int srow = tid >> 2;
    const int sq   = tid & 3;
    const int dq   = (sq ^ ((srow >> 2) & 3)) * 8;
    const int fr   = lane & 15;
    const int fq   = lane >> 4;
    const int rcol = (fq ^ ((fr >> 2) & 3)) * 8;
    const int lrow = lane >> 2, lq = lane & 3;

    for (int k0 = 0; k0 < Kp; k0 += 32) {
        if (AMODE == 0) {
#pragma unroll
            for (int half = 0; half < 2; ++half) {
                int row = half * 64 + srow;
                int kc  = k0 + sq * 8;
                union { u16 s[8]; short8 v; } uh, ul;
                if (kc + 8 <= Kreal) {
                    const float* p = &Af32[(size_t)(m0 + row) * lda + kc];
#pragma unroll
                    for (int j = 0; j < 8; ++j) {
                        float xv = p[j];
                        u16 hh = f32_to_bf16(xv);
                        uh.s[j] = hh;
                        ul.s[j] = f32_to_bf16(xv - bf16_to_f32(hh));
                    }
                } else {
#pragma unroll
                    for (int j = 0; j < 8; ++j) { uh.s[j] = 0; ul.s[j] = 0; }
                }
                *(short8*)&As[0][row][dq] = uh.v;
                *(short8*)&As[1][row][dq] = ul.v;
                size_t wo = (size_t)(n0 + row) * Kp + k0 + sq * 8;
                *(short8*)&Ws[0][row][dq] = *(const short8*)(Whi + wo);
                *(short8*)&Ws[1][row][dq] = *(const short8*)(Wlo + wo);
            }
        } else {
            if (wave < 2) {
                // packed A: 8 stages x 1KB, rows wave*64+g*8 .. +8
                const u32* gA = Apk + (size_t)m0 * lda + k0;
#pragma unroll
                for (int g = 0; g < 8; ++g) {
                    int row = wave * 64 + g * 8 + (lane >> 3);
                    int srcc = (lane & 7) ^ (row & 7);
                    gload16v(gA + (size_t)row * lda + srcc * 4,
                             AsP + (size_t)(wave * 64 + g * 8) * 32);
                }
            } else {
                const u16* gW = ((wave == 2) ? Whi : Wlo) + (size_t)n0 * Kp + k0;
                u16* lbW = (u16*)(smem + 16384) + (wave - 2) * 4096;
#pragma unroll
                for (int g = 0; g < 8; ++g) {
                    int row = g * 16 + lrow;
                    int srcq = lq ^ ((row >> 2) & 3);
                    gload16v(gW + (size_t)row * Kp + srcq * 8, lbW + g * 512);
                }
            }
        }
        __syncthreads();

        short8 ah[4], al[4], wh[4], wl[4];
#pragma unroll
        for (int f = 0; f < 4; ++f) {
            int arow = wm + f * 16 + fr;
            if (AMODE == 0) {
                ah[f] = *(const short8*)&As[0][arow][rcol];
                al[f] = *(const short8*)&As[1][arow][rcol];
            } else {
                int s0 = (((2 * fq) ^ (arow & 7)) << 2);
                int s1 = (((2 * fq + 1) ^ (arow & 7)) << 2);
                u32x4 p0 = *(const u32x4*)&AsP[arow * 32 + s0];
                u32x4 p1 = *(const u32x4*)&AsP[arow * 32 + s1];
                unpack8(p0, p1, ah[f], al[f]);
            }
            int wrow = wn + f * 16 + fr;
            wh[f] = *(const short8*)&Ws[0][wrow][rcol];
            wl[f] = *(const short8*)&Ws[1][wrow][rcol];
        }
#pragma unroll
        for (int i = 0; i < 4; ++i)
#pragma unroll
            for (int j = 0; j < 4; ++j) {
                acc[i][j] = __builtin_amdgcn_mfma_f32_16x16x32_bf16(ah[i], wh[j], acc[i][j], 0, 0, 0);
                acc[i][j] = __builtin_amdgcn_mfma_f32_16x16x32_bf16(ah[i], wl[j], acc[i][j], 0, 0, 0);
                acc[i][j] = __builtin_amdgcn_mfma_f32_16x16x32_bf16(al[i], wh[j], acc[i][j], 0, 0, 0);
            }
        __syncthreads();
    }

    // ---- coalesced epilogue via LDS bounce ----
    const int erow = tid & 31;
    const int echk = tid >> 5;
    const int gm_base = m0 + ((erow >> 4) * 64) + (erow & 15);
    const int gn0 = n0 + echk * 16;
    const bool vec4ok = ((ldc & 3) == 0);

#pragma unroll
    for (int i = 0; i < 4; ++i) {
        __syncthreads();
#pragma unroll
        for (int j = 0; j < 4; ++j)
#pragma unroll
            for (int r = 0; r < 4; ++r)
                Cs[(wave >> 1) * 16 + fq * 4 + r][wn + j * 16 + fr] = acc[i][j][r];
        __syncthreads();

        const int gm = gm_base + i * 16;
        float* crow = C + (size_t)gm * ldc;
        if (gn0 + 16 <= Nreal) {
#pragma unroll
            for (int q = 0; q < 4; ++q) {
                f32x4 v = *(const f32x4*)&Cs[erow][echk * 16 + q * 4];
                if (bias) {
                    f32x4 bv = *(const f32x4*)&bias[gn0 + q * 4];
                    v += bv;
                }
                if (vec4ok) {
                    *(f32x4*)&crow[gn0 + q * 4] = v;
                } else {
                    f32x2 lo2 = {v[0], v[1]}, hi2 = {v[2], v[3]};
                    *(f32x2*)&crow[gn0 + q * 4]     = lo2;
                    *(f32x2*)&crow[gn0 + q * 4 + 2] = hi2;
                }
            }
        } else {
#pragma unroll
            for (int q = 0; q < 4; ++q)
#pragma unroll
                for (int p = 0; p < 4; ++p) {
                    int n = gn0 + q * 4 + p;
                    if (n < Nreal)
                        crow[n] = Cs[erow][echk * 16 + q * 4 + p] + (bias ? bias[n] : 0.f);
                }
        }
    }
}

// ---------------------------------------------------------------------------
// Persistent LSTM, full T steps in one launch. W slice (32 gate-cols, hi+lo)
// in LDS (XOR-swizzled). Depth-6 pipelined k-loop. h transport: packed u32
// (hi|lo) via relaxed agent-scope atomic stores (write-through to coherent
// point) -- NO fences, NO wbl2. Barrier: per-block monotonic flag store +
// per-thread parallel poll. Consumers unpack h via v_perm_b32.
// ---------------------------------------------------------------------------
#define PF(S, KT_) do {                                                        \
    int q_ = (((KT_) * 4 + fq) ^ sxor) * 8;                                    \
    a0h_##S = *(const short8*)&Wlds[rA * Kp + q_];                             \
    a0l_##S = *(const short8*)&Wlds[(32 + rA) * Kp + q_];                      \
    a1h_##S = *(const short8*)&Wlds[rB * Kp + q_];                             \
    a1l_##S = *(const short8*)&Wlds[(32 + rB) * Kp + q_];                      \
    u32x4 u0_ = *(const u32x4*)(hrow + (KT_) * 32 + fq * 8);                   \
    u32x4 u1_ = *(const u32x4*)(hrow + (KT_) * 32 + fq * 8 + 4);               \
    unpack8(u0_, u1_, hh_##S, hl_##S);                                         \
} while (0)

#define CM(S) do {                                                             \
    accA = __builtin_amdgcn_mfma_f32_16x16x32_bf16(a0h_##S, hh_##S, accA, 0, 0, 0); \
    accB = __builtin_amdgcn_mfma_f32_16x16x32_bf16(a1h_##S, hh_##S, accB, 0, 0, 0); \
    accA = __builtin_amdgcn_mfma_f32_16x16x32_bf16(a0h_##S, hl_##S, accA, 0, 0, 0); \
    accB = __builtin_amdgcn_mfma_f32_16x16x32_bf16(a1h_##S, hl_##S, accB, 0, 0, 0); \
    accA = __builtin_amdgcn_mfma_f32_16x16x32_bf16(a0l_##S, hh_##S, accA, 0, 0, 0); \
    accB = __builtin_amdgcn_mfma_f32_16x16x32_bf16(a1l_##S, hh_##S, accB, 0, 0, 0); \
} while (0)

__global__ __launch_bounds__(256, 1) void persistent_lstm(
    const u16* __restrict__ Whi, const u16* __restrict__ Wlo,   // [N4][Kp]
    const u32* __restrict__ h0HL,                               // [64][Kp]
    u32* __restrict__ seqHL,                                    // [T*64][Kp]
    const float* __restrict__ pre,                              // [T*64][N4]
    const float* __restrict__ c_in, float* __restrict__ c_out,  // [64][dout]
    int* __restrict__ flags,                                    // [G] monotonic
    int N4, int Kp, int dout, int G, int TSTEPS)
{
    extern __shared__ __align__(16) u16 Wlds[];   // [2][32][Kp] swizzled
    const int tid  = threadIdx.x;
    const int lane = tid & 63, wave = tid >> 6;
    const int fr = lane & 15, fq = lane >> 4;
    const int c0blk = blockIdx.x * 32;
    const int CH = Kp >> 3;
    const int b = wave * 16 + fr;

    // stage W slice into LDS, chunk slot = q ^ (row&7)
    for (int idx = tid; idx < 64 * CH; idx += 256) {
        int buf = idx / (32 * CH);
        int rem = idx - buf * 32 * CH;
        int r = rem / CH, q = rem - r * CH;
        const u16* src = buf ? Wlo : Whi;
        short8 v = *(const short8*)(src + (size_t)(c0blk + r) * Kp + q * 8);
        *(short8*)&Wlds[(buf * 32 + r) * Kp + (q ^ (r & 7)) * 8] = v;
    }

    const int cA = c0blk + fq * 4;
    const int cB = cA + 16;
    const int jA = cA >> 2, jB = cB >> 2;
    float cregA = c_in[(size_t)b * dout + jA];
    float cregB = c_in[(size_t)b * dout + jB];

    const int rA = fr, rB = 16 + fr;
    const int sxor = fr & 7;
    const int KT = Kp >> 5;            // multiple of 6 by construction

    f32x4 preA = *(const f32x4*)(pre + (size_t)b * N4 + cA);
    f32x4 preB = *(const f32x4*)(pre + (size_t)b * N4 + cB);
    __syncthreads();

    for (int ts = 0; ts < TSTEPS; ++ts) {
        const u32* hbase = (ts == 0) ? h0HL : seqHL + (size_t)(ts - 1) * 64 * Kp;
        const u32* hrow = hbase + (size_t)b * Kp;

        f32x4 accA = {0.f, 0.f, 0.f, 0.f};
        f32x4 accB = {0.f, 0.f, 0.f, 0.f};
        short8 a0h_0, a0l_0, a1h_0, a1l_0, hh_0, hl_0;
        short8 a0h_1, a0l_1, a1h_1, a1l_1, hh_1, hl_1;
        short8 a0h_2, a0l_2, a1h_2, a1l_2, hh_2, hl_2;
        short8 a0h_3, a0l_3, a1h_3, a1l_3, hh_3, hl_3;
        short8 a0h_4, a0l_4, a1h_4, a1l_4, hh_4, hl_4;
        short8 a0h_5, a0l_5, a1h_5, a1l_5, hh_5, hl_5;

        PF(0, 0); PF(1, 1); PF(2, 2); PF(3, 3); PF(4, 4); PF(5, 5);
        for (int kt = 0; kt < KT - 6; kt += 6) {
            CM(0); PF(0, kt + 6);
            CM(1); PF(1, kt + 7);
            CM(2); PF(2, kt + 8);
            CM(3); PF(3, kt + 9);
            CM(4); PF(4, kt + 10);
            CM(5); PF(5, kt + 11);
        }
        CM(0); CM(1); CM(2); CM(3); CM(4); CM(5);

        // epilogue: gates -> c,h ; write packed h (write-through)
#pragma unroll
        for (int ct = 0; ct < 2; ++ct) {
            f32x4 a = ct ? accB : accA;
            f32x4 p = ct ? preB : preA;
            int j  = ct ? jB : jA;
            float gi = a[0] + p[0];
            float gf = a[1] + p[1];
            float gg = a[2] + p[2];
            float go_ = a[3] + p[3];
            float si = 1.f / (1.f + expf(-gi));
            float sf = 1.f / (1.f + expf(-gf));
            float so = 1.f / (1.f + expf(-go_));
            float tg = tanhf(gg);
            float cn = sf * (ct ? cregB : cregA) + si * tg;
            float hv = so * tanhf(cn);
            if (ct) cregB = cn; else cregA = cn;
            u16 hb = f32_to_bf16(hv);
            u16 lb = f32_to_bf16(hv - bf16_to_f32(hb));
            __hip_atomic_store(&seqHL[(size_t)(ts * 64 + b) * Kp + j],
                               (u32)hb | ((u32)lb << 16),
                               __ATOMIC_RELAXED, __HIP_MEMORY_SCOPE_AGENT);
        }

        if (ts != TSTEPS - 1) {
            __syncthreads();   // drain all waves' packed-h stores (vmcnt 0)
            if (tid == 0)
                __hip_atomic_store(&flags[blockIdx.x], ts + 1,
                                   __ATOMIC_RELAXED, __HIP_MEMORY_SCOPE_AGENT);
            // prefetch next-step pre while flags settle
            {
                const float* prow2 = pre + (size_t)((ts + 1) * 64 + b) * N4;
                preA = *(const f32x4*)(prow2 + cA);
                preB = *(const f32x4*)(prow2 + cB);
            }
            if (tid < G) {
                while (__hip_atomic_load(&flags[tid], __ATOMIC_RELAXED,
                                         __HIP_MEMORY_SCOPE_AGENT) < ts + 1)
                    __builtin_amdgcn_s_sleep(1);
            }
            __syncthreads();
            __builtin_amdgcn_sched_barrier(0);
        }
    }

    c_out[(size_t)b * dout + jA] = cregA;
    c_out[(size_t)b * dout + jB] = cregB;
}

// ---------------------------------------------------------------------------
extern "C" void kernel_launch(void* const* d_in, const int* in_sizes, int n_in,
                              void* d_out, int out_size, void* d_ws, size_t ws_size,
                              hipStream_t stream)
{
    const int T = 128, B = 64, EMB = 400, HID = 1152, NTOK = 33278;
    const int TB = T * B;

    const float* x     = (const float*)d_in[0];
    const float* h0[3] = {(const float*)d_in[1], (const float*)d_in[2], (const float*)d_in[3]};
    const float* c0[3] = {(const float*)d_in[4], (const float*)d_in[5], (const float*)d_in[6]};
    const float* W_ih[3] = {(const float*)d_in[7],  (const float*)d_in[11], (const float*)d_in[15]};
    const float* W_hh[3] = {(const float*)d_in[8],  (const float*)d_in[12], (const float*)d_in[16]};
    const float* b_ih[3] = {(const float*)d_in[9],  (const float*)d_in[13], (const float*)d_in[17]};
    const float* b_hh[3] = {(const float*)d_in[10], (const float*)d_in[14], (const float*)d_in[18]};
    const float* W_dec = (const float*)d_in[19];
    const float* b_dec = (const float*)d_in[20];

    const int din[3]    = {EMB, HID, HID};     // input dim per layer
    const int Kpre[3]   = {416, 1152, 1152};   // padded K of pre-GEMM
    const int dh[3]     = {HID, HID, EMB};     // hidden dim per layer
    const int KpH[3]    = {1152, 1152, 576};   // padded h width (KT%6==0)
    const int N4[3]     = {4608, 4608, 1600};
    const int N4p128[3] = {4608, 4608, 1664};
    const int Gp[3]     = {144, 144, 50};      // persistent grid (N4/32)

    char* wsp = (char*)d_ws;
    size_t off = 0;
    auto alloc = [&](size_t bytes) -> char* {
        char* p = wsp + off; off = (off + bytes + 255) & ~(size_t)255; return p;
    };

    float* pre   = (float*)alloc((size_t)TB * 4608 * 4);          // 151 MB (full T)
    u32* seqHL   = (u32*)alloc((size_t)TB * 1152 * 4);            // 37.7 MB packed h
    u16* WihHi   = (u16*)alloc((size_t)4608 * 1152 * 2);          // 10.6 MB
    u16* WihLo   = (u16*)alloc((size_t)4608 * 1152 * 2);
    u16* WhhHi   = (u16*)alloc((size_t)4608 * 1152 * 2);
    u16* WhhLo   = (u16*)alloc((size_t)4608 * 1152 * 2);
    u32* h0HL    = (u32*)alloc((size_t)B * 1152 * 4);
    float* bsum  = (float*)alloc(4608 * 4);
    float* cstb  = (float*)alloc((size_t)B * HID * 4);
    int* flags   = (int*)alloc(3 * 256 * 4);
    // decoder W split aliases pre (pre dead by then): 2 x 27.7 MB <= 151 MB
    u16* WdecHi  = (u16*)pre;
    u16* WdecLo  = (u16*)pre + (size_t)33280 * 416;

    hipMemsetAsync(flags, 0, 3 * 256 * 4, stream);
    hipFuncSetAttribute(reinterpret_cast<const void*>(persistent_lstm),
                        hipFuncAttributeMaxDynamicSharedMemorySize, 160 * 1024);
    hipFuncSetAttribute(reinterpret_cast<const void*>(&gemm3m<0>),
                        hipFuncAttributeMaxDynamicSharedMemorySize, 64 * 1024);
    hipFuncSetAttribute(reinterpret_cast<const void*>(&gemm3m<2>),
                        hipFuncAttributeMaxDynamicSharedMemorySize, 64 * 1024);

    auto run_split = [&](const float* src, u16* hi, u16* lo,
                         int N, int K, int Npad, int Kpad, int perm) {
        int total = Npad * Kpad;
        split_pad_kernel<<<(total + 255) / 256, 256, 0, stream>>>(
            src, hi, lo, N, K, Npad, Kpad, perm);
    };

    for (int l = 0; l < 3; ++l) {
        run_split(W_hh[l], WhhHi, WhhLo, N4[l], dh[l], N4[l], KpH[l], 1);
        pack_h0_kernel<<<(B * KpH[l] + 255) / 256, 256, 0, stream>>>(
            h0[l], h0HL, B, dh[l], KpH[l]);
        run_split(W_ih[l], WihHi, WihLo, N4[l], din[l], N4p128[l], Kpre[l], 1);
        bias_perm_kernel<<<(N4[l] + 255) / 256, 256, 0, stream>>>(
            b_ih[l], b_hh[l], bsum, N4[l]);

        const int NT = N4p128[l] / 128;
        const size_t ldsB = (size_t)128 * KpH[l];   // 2*32*Kp*2 bytes

        // pre = X_seq @ W_ih^T + b_ih + b_hh  (full T, M = 8192)
        if (l == 0) {
            gemm3m<0><<<dim3(NT * 64), 256, 32768, stream>>>(
                x, nullptr, WihHi, WihLo, bsum, pre,
                N4[l], EMB, Kpre[l], EMB, N4[l]);
        } else {
            gemm3m<2><<<dim3(NT * 64), 256, 32768, stream>>>(
                nullptr, seqHL, WihHi, WihLo, bsum, pre,
                N4[l], KpH[l-1], KpH[l-1], KpH[l-1], N4[l]);
        }

        persistent_lstm<<<dim3(Gp[l]), 256, ldsB, stream>>>(
            WhhHi, WhhLo, h0HL, seqHL, pre,
            c0[l], cstb, flags + l * 256,
            N4[l], KpH[l], dh[l], Gp[l], T);
    }

    // zero decoder A-pad cols 400..415 (stride 576), then decoder GEMM
    zero_cols_kernel<<<(TB * 16 + 255) / 256, 256, 0, stream>>>(
        seqHL, TB, 400, 416, 576);
    run_split(W_dec, WdecHi, WdecLo, NTOK, EMB, 33280, 416, 0);
    gemm3m<2><<<dim3(260 * 64), 256, 32768, stream>>>(
        nullptr, seqHL, WdecHi, WdecLo, b_dec, (float*)d_out,
        NTOK, 416, 416, 576, NTOK);
}